// Round 4
// baseline (191.576 us; speedup 1.0000x reference)
//
#include <hip/hip_runtime.h>

// B=4, S=4096, D_IN=1024, D_QK=D_V=64
// out = softmax(relu(XWq+bq) @ relu(XWk+bk)^T) @ relu(XWv+bv) * mask

typedef short s16x8 __attribute__((ext_vector_type(8)));   // 8 bf16 (4 VGPRs) MFMA frag
typedef float fx4   __attribute__((ext_vector_type(4)));   // MFMA accum frag
typedef unsigned short u16x4 __attribute__((ext_vector_type(4)));

#define LOG2E 1.4426950408889634f

__device__ __forceinline__ unsigned short f2bf(float x) {   // fp32 -> bf16 RTN
    unsigned int u = __float_as_uint(x);
    u += 0x7FFFu + ((u >> 16) & 1u);
    return (unsigned short)(u >> 16);
}
__device__ __forceinline__ float bf2f(unsigned short b) {
    return __uint_as_float(((unsigned int)b) << 16);
}

// ---------------------------------------------------------------------------
// Kernel 1: split W{q,k,v} [1024][64] fp32 into W^T hi/lo bf16 [3][64][1024]
// ---------------------------------------------------------------------------
__global__ __launch_bounds__(256) void prep_w_kernel(
    const float* __restrict__ Wq, const float* __restrict__ Wk, const float* __restrict__ Wv,
    unsigned short* __restrict__ wt_hi, unsigned short* __restrict__ wt_lo)
{
    int idx = blockIdx.x * 256 + threadIdx.x;   // 3*1024*64 = 196608 threads
    int y = idx >> 16;
    int r = idx & 65535;
    int k = r >> 6;
    int c = r & 63;
    const float* W = (y == 0) ? Wq : (y == 1) ? Wk : Wv;
    float x = W[r];
    unsigned short h = f2bf(x);
    unsigned short l = f2bf(x - bf2f(h));
    int o = (y * 64 + c) * 1024 + k;
    wt_hi[o] = h; wt_lo[o] = l;
}

// ---------------------------------------------------------------------------
// Kernel 2: projection. grid (3, 256). M-tile 64. Software-pipelined: X/W
// tiles for iter kc+1 are loaded into registers before iter kc's MFMAs,
// hiding HBM latency behind compute. Compensated bf16 MFMA (hh+hl+lh).
// y==0 -> q_hi/q_lo bf16; y==1 -> k bf16; y==2 -> V^T [b][d][s] bf16.
// ---------------------------------------------------------------------------
__global__ __launch_bounds__(256, 4) void proj_kernel(
    const float* __restrict__ X,
    const unsigned short* __restrict__ wt_hi, const unsigned short* __restrict__ wt_lo,
    const float* __restrict__ bq, const float* __restrict__ bk, const float* __restrict__ bv,
    unsigned short* __restrict__ q_hi, unsigned short* __restrict__ q_lo,
    unsigned short* __restrict__ k_bf, unsigned short* __restrict__ vt_g)
{
    __shared__ __align__(16) unsigned short a_hi[64][72];   // X tile hi, +8 pad
    __shared__ __align__(16) unsigned short a_lo[64][72];
    __shared__ __align__(16) unsigned short b_hi[64][72];   // W^T tile hi [col][k]
    __shared__ __align__(16) unsigned short b_lo[64][72];

    const int tid  = threadIdx.x;
    const int lane = tid & 63;
    const int w    = tid >> 6;
    const int quad = lane >> 4;
    const int l15  = lane & 15;
    const int y    = blockIdx.x;        // 0=q 1=k 2=v
    const int m0   = blockIdx.y * 64;   // global row (b*4096+s)

    fx4 acc[4];
    #pragma unroll
    for (int nt = 0; nt < 4; nt++)
        acc[nt] = (fx4){0.f, 0.f, 0.f, 0.f};

    // prefetch registers
    fx4   xr[4];
    s16x8 wrh[2], wrl[2];
    const int xrow = tid >> 4;
    const int xoff = (tid & 15) * 4;
    const int wrow = tid >> 3;
    const int woff = (tid & 7) * 8;

    #pragma unroll
    for (int i = 0; i < 4; i++)
        xr[i] = *(const fx4*)(X + (size_t)(m0 + xrow + i * 16) * 1024 + xoff);
    #pragma unroll
    for (int i = 0; i < 2; i++) {
        size_t g = (size_t)(y * 64 + wrow + i * 32) * 1024 + woff;
        wrh[i] = *(const s16x8*)(wt_hi + g);
        wrl[i] = *(const s16x8*)(wt_lo + g);
    }

    for (int kc = 0; kc < 16; kc++) {
        if (kc) __syncthreads();   // prev iter's LDS readers done
        // convert & write staged registers to LDS
        #pragma unroll
        for (int i = 0; i < 4; i++) {
            fx4 xv = xr[i];
            unsigned short h0 = f2bf(xv.x), h1 = f2bf(xv.y), h2 = f2bf(xv.z), h3 = f2bf(xv.w);
            unsigned short l0 = f2bf(xv.x - bf2f(h0)), l1 = f2bf(xv.y - bf2f(h1));
            unsigned short l2 = f2bf(xv.z - bf2f(h2)), l3 = f2bf(xv.w - bf2f(h3));
            *(u16x4*)&a_hi[xrow + i * 16][xoff] = (u16x4){h0, h1, h2, h3};
            *(u16x4*)&a_lo[xrow + i * 16][xoff] = (u16x4){l0, l1, l2, l3};
        }
        #pragma unroll
        for (int i = 0; i < 2; i++) {
            *(s16x8*)&b_hi[wrow + i * 32][woff] = wrh[i];
            *(s16x8*)&b_lo[wrow + i * 32][woff] = wrl[i];
        }
        __syncthreads();

        // prefetch next tile into registers (latency hidden behind MFMAs)
        if (kc < 15) {
            #pragma unroll
            for (int i = 0; i < 4; i++)
                xr[i] = *(const fx4*)(X + (size_t)(m0 + xrow + i * 16) * 1024 + (kc + 1) * 64 + xoff);
            #pragma unroll
            for (int i = 0; i < 2; i++) {
                size_t g = (size_t)(y * 64 + wrow + i * 32) * 1024 + (kc + 1) * 64 + woff;
                wrh[i] = *(const s16x8*)(wt_hi + g);
                wrl[i] = *(const s16x8*)(wt_lo + g);
            }
        }

        s16x8 ah[2], al[2];
        #pragma unroll
        for (int ks = 0; ks < 2; ks++) {
            int r = w * 16 + l15;
            ah[ks] = *(const s16x8*)&a_hi[r][ks * 32 + quad * 8];
            al[ks] = *(const s16x8*)&a_lo[r][ks * 32 + quad * 8];
        }
        #pragma unroll
        for (int nt = 0; nt < 4; nt++) {
            #pragma unroll
            for (int ks = 0; ks < 2; ks++) {
                s16x8 bh = *(const s16x8*)&b_hi[nt * 16 + l15][ks * 32 + quad * 8];
                s16x8 bl = *(const s16x8*)&b_lo[nt * 16 + l15][ks * 32 + quad * 8];
                acc[nt] = __builtin_amdgcn_mfma_f32_16x16x32_bf16(ah[ks], bh, acc[nt], 0, 0, 0);
                acc[nt] = __builtin_amdgcn_mfma_f32_16x16x32_bf16(ah[ks], bl, acc[nt], 0, 0, 0);
                acc[nt] = __builtin_amdgcn_mfma_f32_16x16x32_bf16(al[ks], bh, acc[nt], 0, 0, 0);
            }
        }
    }
    __syncthreads();

    // epilogue: bias + relu, write per-matrix
    const float* bias = (y == 0) ? bq : (y == 1) ? bk : bv;
    const int b   = m0 >> 12;
    const int s0b = m0 & 4095;
    unsigned short* vtr = (unsigned short*)&a_hi[0][0];  // alias: [64 d][72] (s-padded)

    #pragma unroll
    for (int nt = 0; nt < 4; nt++) {
        int col = nt * 16 + l15;
        float bb = bias[col];
        int rloc = w * 16 + quad * 4;   // local row 0..63
        #pragma unroll
        for (int r = 0; r < 4; r++) {
            float v = acc[nt][r] + bb;
            v = fmaxf(v, 0.f);
            size_t grow = (size_t)(m0 + rloc + r);
            if (y == 0) {
                unsigned short h = f2bf(v);
                unsigned short l = f2bf(v - bf2f(h));
                q_hi[grow * 64 + col] = h;
                q_lo[grow * 64 + col] = l;
            } else if (y == 1) {
                k_bf[grow * 64 + col] = f2bf(v);
            } else {
                vtr[col * 72 + rloc + r] = f2bf(v);  // transpose via LDS
            }
        }
    }
    if (y == 2) {
        __syncthreads();
        #pragma unroll
        for (int i = 0; i < 2; i++) {
            int c = tid + i * 256;
            int row = c >> 3;           // d 0..63
            int off = (c & 7) * 8;      // s chunk
            s16x8 vv = *(const s16x8*)&vtr[row * 72 + off];
            *(s16x8*)(vt_g + (size_t)(b * 64 + row) * 4096 + s0b + off) = vv;
        }
    }
}

// ---------------------------------------------------------------------------
// Kernel 3: fused attention, KV-split. grid (32 qtiles, NCK chunks, 4 batch).
// Block = 128 q-rows, 4 waves; each WAVE owns 32 q-rows (2x 16-row subtiles)
// so kt/vt LDS fragment reads are amortized over 2x rows vs round-3.
// Writes UNNORMALIZED partial O and row-sum l; combine reduces over chunks.
// No online max: q,k >= 0 post-relu => exp safe in fp32.
// ---------------------------------------------------------------------------
__global__ __launch_bounds__(256) void attn_kernel(
    const unsigned short* __restrict__ q_hi, const unsigned short* __restrict__ q_lo,
    const unsigned short* __restrict__ k_bf, const unsigned short* __restrict__ vt_g,
    float* __restrict__ pO, float* __restrict__ pL, int ipc)
{
    __shared__ __align__(16) unsigned short kt[64][72];      // [key][dim]
    __shared__ __align__(16) unsigned short vt[64][72];      // [dim][key]  (V^T)
    __shared__ __align__(16) unsigned short pt[4][32][72];   // per-wave P [q][key]

    const int tid  = threadIdx.x;
    const int lane = tid & 63;
    const int w    = tid >> 6;
    const int quad = lane >> 4;
    const int l15  = lane & 15;
    const int ck   = blockIdx.y;
    const int b    = blockIdx.z;
    const int q0   = blockIdx.x * 128;   // within batch

    // Q fragments for 2 row-subtiles (A layout: m=lane&15, k=quad*8+j), hi/lo
    s16x8 qh0[2], qh1[2], ql0[2], ql1[2];
    #pragma unroll
    for (int st = 0; st < 2; st++) {
        const size_t qoff = ((size_t)b * 4096 + q0 + w * 32 + st * 16 + l15) * 64 + quad * 8;
        qh0[st] = *(const s16x8*)(q_hi + qoff);
        qh1[st] = *(const s16x8*)(q_hi + qoff + 32);
        ql0[st] = *(const s16x8*)(q_lo + qoff);
        ql1[st] = *(const s16x8*)(q_lo + qoff + 32);
    }

    fx4 accO[2][4];
    float lsum[2][4];
    #pragma unroll
    for (int st = 0; st < 2; st++)
        #pragma unroll
        for (int nt = 0; nt < 4; nt++) {
            accO[st][nt] = (fx4){0.f, 0.f, 0.f, 0.f};
            lsum[st][nt & 3] = 0.f;
        }
    #pragma unroll
    for (int st = 0; st < 2; st++)
        #pragma unroll
        for (int r = 0; r < 4; r++) lsum[st][r] = 0.f;

    const unsigned short* kgb = k_bf + (size_t)b * 4096 * 64;  // [s][64]
    const unsigned short* vgb = vt_g + (size_t)b * 64 * 4096;  // [d][s]

    const int srow = tid >> 3;
    const int soff = (tid & 7) * 8;

    for (int it = ck * ipc; it < ck * ipc + ipc; it++) {
        const unsigned short* kg = kgb + (size_t)it * 4096;    // 64 keys x 64 dims
        #pragma unroll
        for (int i = 0; i < 2; i++) {
            int row = srow + i * 32;
            *(s16x8*)&kt[row][soff] = *(const s16x8*)(kg + (size_t)row * 64 + soff);
            *(s16x8*)&vt[row][soff] = *(const s16x8*)(vgb + (size_t)row * 4096 + it * 64 + soff);
        }
        __syncthreads();

        // S = Q K^T (hi/lo compensated); kt reads shared across both subtiles
        #pragma unroll
        for (int nt = 0; nt < 4; nt++) {
            s16x8 k0 = *(const s16x8*)&kt[nt * 16 + l15][quad * 8];
            s16x8 k1 = *(const s16x8*)&kt[nt * 16 + l15][32 + quad * 8];
            #pragma unroll
            for (int st = 0; st < 2; st++) {
                fx4 sc = (fx4){0.f, 0.f, 0.f, 0.f};
                sc = __builtin_amdgcn_mfma_f32_16x16x32_bf16(qh0[st], k0, sc, 0, 0, 0);
                sc = __builtin_amdgcn_mfma_f32_16x16x32_bf16(ql0[st], k0, sc, 0, 0, 0);
                sc = __builtin_amdgcn_mfma_f32_16x16x32_bf16(qh1[st], k1, sc, 0, 0, 0);
                sc = __builtin_amdgcn_mfma_f32_16x16x32_bf16(ql1[st], k1, sc, 0, 0, 0);
                // P = exp(S) -> bf16 -> LDS (C layout -> A layout round trip)
                #pragma unroll
                for (int r = 0; r < 4; r++) {
                    float p = __builtin_amdgcn_exp2f(sc[r] * LOG2E);
                    unsigned short pb = f2bf(p);
                    lsum[st][r] += bf2f(pb);
                    pt[w][st * 16 + quad * 4 + r][nt * 16 + l15] = pb;
                }
            }
        }

        // O += P V ; pa reads reused across nt, vt reads shared across st
        s16x8 pa0[2], pa1[2];
        #pragma unroll
        for (int st = 0; st < 2; st++) {
            pa0[st] = *(const s16x8*)&pt[w][st * 16 + l15][quad * 8];
            pa1[st] = *(const s16x8*)&pt[w][st * 16 + l15][32 + quad * 8];
        }
        #pragma unroll
        for (int nt = 0; nt < 4; nt++) {
            s16x8 v0 = *(const s16x8*)&vt[nt * 16 + l15][quad * 8];
            s16x8 v1 = *(const s16x8*)&vt[nt * 16 + l15][32 + quad * 8];
            #pragma unroll
            for (int st = 0; st < 2; st++) {
                accO[st][nt] = __builtin_amdgcn_mfma_f32_16x16x32_bf16(pa0[st], v0, accO[st][nt], 0, 0, 0);
                accO[st][nt] = __builtin_amdgcn_mfma_f32_16x16x32_bf16(pa1[st], v1, accO[st][nt], 0, 0, 0);
            }
        }
        __syncthreads();
    }

    // reduce row-sums across the 16 lanes sharing each row group
    #pragma unroll
    for (int st = 0; st < 2; st++)
        #pragma unroll
        for (int r = 0; r < 4; r++) {
            float v = lsum[st][r];
            #pragma unroll
            for (int o = 1; o < 16; o <<= 1) v += __shfl_xor(v, o);
            lsum[st][r] = v;
        }
    // write partials: pO[ck][b*4096+q][64], pL[ck][b*4096+q]
    #pragma unroll
    for (int st = 0; st < 2; st++)
        #pragma unroll
        for (int r = 0; r < 4; r++) {
            int qrow = q0 + w * 32 + st * 16 + quad * 4 + r;
            size_t grow = (size_t)b * 4096 + qrow;
            #pragma unroll
            for (int nt = 0; nt < 4; nt++)
                pO[((size_t)ck * 16384 + grow) * 64 + nt * 16 + l15] = accO[st][nt][r];
            if (l15 == 0)
                pL[(size_t)ck * 16384 + grow] = lsum[st][r];
        }
}

// ---------------------------------------------------------------------------
// Kernel 4: combine partials: out = (sum_c pO) * mask / (sum_c pL)
// ---------------------------------------------------------------------------
__global__ __launch_bounds__(256) void combine_kernel(
    const float* __restrict__ pO, const float* __restrict__ pL,
    const float* __restrict__ mask, float* __restrict__ out, int nck)
{
    int idx = blockIdx.x * 256 + threadIdx.x;   // 262144 = (b*4096+s)*16 + dgrp
    int q  = idx >> 4;
    int dg = idx & 15;
    fx4 s = (fx4){0.f, 0.f, 0.f, 0.f};
    float l = 0.f;
    for (int c = 0; c < nck; c++) {
        s += *(const fx4*)(pO + ((size_t)c * 16384 + q) * 64 + dg * 4);
        l += pL[(size_t)c * 16384 + q];
    }
    float scale = mask[q] / l;
    *(fx4*)(out + (size_t)q * 64 + dg * 4) = s * scale;
}

// ---------------------------------------------------------------------------
extern "C" void kernel_launch(void* const* d_in, const int* in_sizes, int n_in,
                              void* d_out, int out_size, void* d_ws, size_t ws_size,
                              hipStream_t stream)
{
    const float* X    = (const float*)d_in[0];
    const float* mask = (const float*)d_in[1];
    const float* Wq   = (const float*)d_in[2];
    const float* bq   = (const float*)d_in[3];
    const float* Wk   = (const float*)d_in[4];
    const float* bk   = (const float*)d_in[5];
    const float* Wv   = (const float*)d_in[6];
    const float* bv   = (const float*)d_in[7];
    float* out = (float*)d_out;

    char* ws = (char*)d_ws;
    unsigned short* q_hi  = (unsigned short*)(ws);                       // 2 MB
    unsigned short* q_lo  = (unsigned short*)(ws + (size_t)(2u << 20));  // 2 MB
    unsigned short* k_bf  = (unsigned short*)(ws + (size_t)(4u << 20));  // 2 MB
    unsigned short* vt_g  = (unsigned short*)(ws + (size_t)(6u << 20));  // 2 MB  [b][d][s]
    unsigned short* wt_hi = (unsigned short*)(ws + (size_t)(8u << 20));  // 384 KB
    unsigned short* wt_lo = (unsigned short*)(ws + (size_t)(8u << 20) + 393216);
    float*          pO    = (float*)(ws + (size_t)(9u << 20));           // nck*4 MB

    // chunk count: 8 if workspace allows (41.5 MB), else 4 (25.25 MB)
    size_t need8 = (size_t)(9u << 20) + 8ull * ((4u << 20) + 65536u);
    int nck = (ws_size >= need8) ? 8 : 4;
    int ipc = 64 / nck;
    float* pL = (float*)(ws + (size_t)(9u << 20) + (size_t)nck * (4u << 20));

    hipLaunchKernelGGL(prep_w_kernel, dim3(768), dim3(256), 0, stream,
                       Wq, Wk, Wv, wt_hi, wt_lo);
    hipLaunchKernelGGL(proj_kernel, dim3(3, 256), dim3(256), 0, stream,
                       X, wt_hi, wt_lo, bq, bk, bv, q_hi, q_lo, k_bf, vt_g);
    hipLaunchKernelGGL(attn_kernel, dim3(32, nck, 4), dim3(256), 0, stream,
                       q_hi, q_lo, k_bf, vt_g, pO, pL, ipc);
    hipLaunchKernelGGL(combine_kernel, dim3(1024), dim3(256), 0, stream,
                       pO, pL, mask, out, nck);
}

// Round 5
// 177.554 us; speedup vs baseline: 1.0790x; 1.0790x over previous
//
#include <hip/hip_runtime.h>

// B=4, S=4096, D_IN=1024, D_QK=D_V=64
// out = softmax(relu(XWq+bq) @ relu(XWk+bk)^T) @ relu(XWv+bv) * mask

typedef short s16x8 __attribute__((ext_vector_type(8)));   // 8 bf16 (4 VGPRs) MFMA frag
typedef float fx4   __attribute__((ext_vector_type(4)));   // MFMA accum frag
typedef unsigned short u16x4 __attribute__((ext_vector_type(4)));

#define LOG2E 1.4426950408889634f

__device__ __forceinline__ unsigned short f2bf(float x) {   // fp32 -> bf16 RTN
    unsigned int u = __float_as_uint(x);
    u += 0x7FFFu + ((u >> 16) & 1u);
    return (unsigned short)(u >> 16);
}
__device__ __forceinline__ float bf2f(unsigned short b) {
    return __uint_as_float(((unsigned int)b) << 16);
}

// ---------------------------------------------------------------------------
// Kernel 1: split W{q,k,v} [1024][64] fp32 into W^T hi/lo bf16 [3][64][1024]
// ---------------------------------------------------------------------------
__global__ __launch_bounds__(256) void prep_w_kernel(
    const float* __restrict__ Wq, const float* __restrict__ Wk, const float* __restrict__ Wv,
    unsigned short* __restrict__ wt_hi, unsigned short* __restrict__ wt_lo)
{
    int idx = blockIdx.x * 256 + threadIdx.x;   // 3*1024*64 = 196608 threads
    int y = idx >> 16;
    int r = idx & 65535;
    int k = r >> 6;
    int c = r & 63;
    const float* W = (y == 0) ? Wq : (y == 1) ? Wk : Wv;
    float x = W[r];
    unsigned short h = f2bf(x);
    unsigned short l = f2bf(x - bf2f(h));
    int o = (y * 64 + c) * 1024 + k;
    wt_hi[o] = h; wt_lo[o] = l;
}

// ---------------------------------------------------------------------------
// Kernel 2: projection. grid (3, 256), block 512 (8 waves = 4 row-subtiles x
// 2 col-halves). M-tile 64. LDS 36.9 KB -> 3 blocks/CU resident (grid = 3/CU
// exactly) = 24 waves/CU = 75% occupancy (was ~12 waves). Register-prefetch
// pipeline kept. Compensated bf16 MFMA (hh+hl+lh ~ fp32).
// y==0 -> q_hi/q_lo bf16; y==1 -> k bf16; y==2 -> V^T [b][d][s] bf16.
// ---------------------------------------------------------------------------
__global__ __launch_bounds__(512, 6) void proj_kernel(
    const float* __restrict__ X,
    const unsigned short* __restrict__ wt_hi, const unsigned short* __restrict__ wt_lo,
    const float* __restrict__ bq, const float* __restrict__ bk, const float* __restrict__ bv,
    unsigned short* __restrict__ q_hi, unsigned short* __restrict__ q_lo,
    unsigned short* __restrict__ k_bf, unsigned short* __restrict__ vt_g)
{
    __shared__ __align__(16) unsigned short a_buf[2][64][72];  // X tile hi/lo, +8 pad
    __shared__ __align__(16) unsigned short b_hi[64][72];      // W^T tile hi [col][k]
    __shared__ __align__(16) unsigned short b_lo[64][72];

    const int tid  = threadIdx.x;
    const int lane = tid & 63;
    const int w    = tid >> 6;      // 0..7
    const int quad = lane >> 4;
    const int l15  = lane & 15;
    const int rs   = w & 3;         // row-subtile (16 rows)
    const int ch   = w >> 2;        // col half (32 cols)
    const int y    = blockIdx.x;    // 0=q 1=k 2=v
    const int m0   = blockIdx.y * 64;

    fx4 acc[2];
    acc[0] = (fx4){0.f, 0.f, 0.f, 0.f};
    acc[1] = (fx4){0.f, 0.f, 0.f, 0.f};

    // prefetch registers
    const int xrow = tid >> 4;        // 0..31
    const int xoff = (tid & 15) * 4;
    const int wrow = tid >> 3;        // 0..63
    const int woff = (tid & 7) * 8;

    fx4   xr[2];
    s16x8 wrh, wrl;
    #pragma unroll
    for (int i = 0; i < 2; i++)
        xr[i] = *(const fx4*)(X + (size_t)(m0 + xrow + i * 32) * 1024 + xoff);
    {
        size_t g = (size_t)(y * 64 + wrow) * 1024 + woff;
        wrh = *(const s16x8*)(wt_hi + g);
        wrl = *(const s16x8*)(wt_lo + g);
    }

    for (int kc = 0; kc < 16; kc++) {
        if (kc) __syncthreads();   // prev iter's LDS readers done
        #pragma unroll
        for (int i = 0; i < 2; i++) {
            fx4 xv = xr[i];
            unsigned short h0 = f2bf(xv.x), h1 = f2bf(xv.y), h2 = f2bf(xv.z), h3 = f2bf(xv.w);
            unsigned short l0 = f2bf(xv.x - bf2f(h0)), l1 = f2bf(xv.y - bf2f(h1));
            unsigned short l2 = f2bf(xv.z - bf2f(h2)), l3 = f2bf(xv.w - bf2f(h3));
            *(u16x4*)&a_buf[0][xrow + i * 32][xoff] = (u16x4){h0, h1, h2, h3};
            *(u16x4*)&a_buf[1][xrow + i * 32][xoff] = (u16x4){l0, l1, l2, l3};
        }
        *(s16x8*)&b_hi[wrow][woff] = wrh;
        *(s16x8*)&b_lo[wrow][woff] = wrl;
        __syncthreads();

        // prefetch next tile into registers (latency hidden behind MFMAs)
        if (kc < 15) {
            #pragma unroll
            for (int i = 0; i < 2; i++)
                xr[i] = *(const fx4*)(X + (size_t)(m0 + xrow + i * 32) * 1024 + (kc + 1) * 64 + xoff);
            size_t g = (size_t)(y * 64 + wrow) * 1024 + (kc + 1) * 64 + woff;
            wrh = *(const s16x8*)(wt_hi + g);
            wrl = *(const s16x8*)(wt_lo + g);
        }

        s16x8 ah[2], al[2];
        #pragma unroll
        for (int ks = 0; ks < 2; ks++) {
            int r = rs * 16 + l15;
            ah[ks] = *(const s16x8*)&a_buf[0][r][ks * 32 + quad * 8];
            al[ks] = *(const s16x8*)&a_buf[1][r][ks * 32 + quad * 8];
        }
        #pragma unroll
        for (int nt = 0; nt < 2; nt++) {
            #pragma unroll
            for (int ks = 0; ks < 2; ks++) {
                s16x8 bh = *(const s16x8*)&b_hi[ch * 32 + nt * 16 + l15][ks * 32 + quad * 8];
                s16x8 bl = *(const s16x8*)&b_lo[ch * 32 + nt * 16 + l15][ks * 32 + quad * 8];
                acc[nt] = __builtin_amdgcn_mfma_f32_16x16x32_bf16(ah[ks], bh, acc[nt], 0, 0, 0);
                acc[nt] = __builtin_amdgcn_mfma_f32_16x16x32_bf16(ah[ks], bl, acc[nt], 0, 0, 0);
                acc[nt] = __builtin_amdgcn_mfma_f32_16x16x32_bf16(al[ks], bh, acc[nt], 0, 0, 0);
            }
        }
    }
    __syncthreads();   // all MFMA LDS reads done before vtr alias writes

    // epilogue: bias + relu, write per-matrix
    const float* bias = (y == 0) ? bq : (y == 1) ? bk : bv;
    const int b   = m0 >> 12;
    const int s0b = m0 & 4095;
    unsigned short* vtr = &a_buf[0][0][0];  // alias: [64 d][72] (s index 0..63)

    #pragma unroll
    for (int nt = 0; nt < 2; nt++) {
        int col = ch * 32 + nt * 16 + l15;
        float bb = bias[col];
        int rloc = rs * 16 + quad * 4;   // local row 0..63
        #pragma unroll
        for (int r = 0; r < 4; r++) {
            float v = acc[nt][r] + bb;
            v = fmaxf(v, 0.f);
            size_t grow = (size_t)(m0 + rloc + r);
            if (y == 0) {
                unsigned short h = f2bf(v);
                unsigned short l = f2bf(v - bf2f(h));
                q_hi[grow * 64 + col] = h;
                q_lo[grow * 64 + col] = l;
            } else if (y == 1) {
                k_bf[grow * 64 + col] = f2bf(v);
            } else {
                vtr[col * 72 + rloc + r] = f2bf(v);  // transpose via LDS
            }
        }
    }
    if (y == 2) {
        __syncthreads();
        int row = tid >> 3;          // d 0..63
        int off = (tid & 7) * 8;     // s chunk
        s16x8 vv = *(const s16x8*)&vtr[row * 72 + off];
        *(s16x8*)(vt_g + (size_t)(b * 64 + row) * 4096 + s0b + off) = vv;
    }
}

// ---------------------------------------------------------------------------
// Kernel 3: fused attention, KV-split. grid (64 qtiles, 8 chunks, 4 batch) =
// 2048 blocks. Block = 64 q-rows, 4 waves, 8 KV tiles each. LDS cut to
// 23.5 KB (pt halved: keys processed in two 32-key halves, QK->exp->pt->PV
// per half; pt is wave-private so no extra barriers) -> 6 blocks/CU = 24
// waves/CU. Writes UNNORMALIZED partial O (bf16) and row-sum l (fp32).
// No online max: q,k >= 0 post-relu => exp safe in fp32.
// ---------------------------------------------------------------------------
__global__ __launch_bounds__(256, 6) void attn_kernel(
    const unsigned short* __restrict__ q_hi, const unsigned short* __restrict__ q_lo,
    const unsigned short* __restrict__ k_bf, const unsigned short* __restrict__ vt_g,
    unsigned short* __restrict__ pOb, float* __restrict__ pL)
{
    __shared__ __align__(16) unsigned short kt[64][72];      // [key][dim]
    __shared__ __align__(16) unsigned short vt[64][72];      // [dim][key]  (V^T)
    __shared__ __align__(16) unsigned short pt[4][16][40];   // per-wave P [q][key half]

    const int tid  = threadIdx.x;
    const int lane = tid & 63;
    const int w    = tid >> 6;
    const int quad = lane >> 4;
    const int l15  = lane & 15;
    const int ck   = blockIdx.y;         // key chunk (512 keys)
    const int b    = blockIdx.z;
    const int q0   = blockIdx.x * 64;    // within batch

    // Q fragments (A layout: m=lane&15, k=quad*8+j), split hi/lo
    const size_t qoff = ((size_t)b * 4096 + q0 + w * 16 + l15) * 64 + quad * 8;
    s16x8 qh0 = *(const s16x8*)(q_hi + qoff);
    s16x8 qh1 = *(const s16x8*)(q_hi + qoff + 32);
    s16x8 ql0 = *(const s16x8*)(q_lo + qoff);
    s16x8 ql1 = *(const s16x8*)(q_lo + qoff + 32);

    fx4 accO[4];
    #pragma unroll
    for (int nt = 0; nt < 4; nt++) accO[nt] = (fx4){0.f, 0.f, 0.f, 0.f};
    float lsum[4] = {0.f, 0.f, 0.f, 0.f};

    const unsigned short* kgb = k_bf + (size_t)b * 4096 * 64;  // [s][64]
    const unsigned short* vgb = vt_g + (size_t)b * 64 * 4096;  // [d][s]

    const int srow = tid >> 3;        // 0..31
    const int soff = (tid & 7) * 8;

    for (int it = ck * 8; it < ck * 8 + 8; it++) {
        const unsigned short* kg = kgb + (size_t)it * 4096;    // 64 keys x 64 dims
        #pragma unroll
        for (int i = 0; i < 2; i++) {
            int row = srow + i * 32;
            *(s16x8*)&kt[row][soff] = *(const s16x8*)(kg + (size_t)row * 64 + soff);
            *(s16x8*)&vt[row][soff] = *(const s16x8*)(vgb + (size_t)row * 4096 + it * 64 + soff);
        }
        __syncthreads();

        #pragma unroll
        for (int kh = 0; kh < 2; kh++) {
            // S = Q K^T for 32-key half (hi/lo compensated)
            #pragma unroll
            for (int nt2 = 0; nt2 < 2; nt2++) {
                int key = kh * 32 + nt2 * 16 + l15;
                s16x8 k0 = *(const s16x8*)&kt[key][quad * 8];
                s16x8 k1 = *(const s16x8*)&kt[key][32 + quad * 8];
                fx4 sc = (fx4){0.f, 0.f, 0.f, 0.f};
                sc = __builtin_amdgcn_mfma_f32_16x16x32_bf16(qh0, k0, sc, 0, 0, 0);
                sc = __builtin_amdgcn_mfma_f32_16x16x32_bf16(ql0, k0, sc, 0, 0, 0);
                sc = __builtin_amdgcn_mfma_f32_16x16x32_bf16(qh1, k1, sc, 0, 0, 0);
                sc = __builtin_amdgcn_mfma_f32_16x16x32_bf16(ql1, k1, sc, 0, 0, 0);
                // P = exp(S) -> bf16 -> wave-private LDS (C -> A layout)
                #pragma unroll
                for (int r = 0; r < 4; r++) {
                    float p = __builtin_amdgcn_exp2f(sc[r] * LOG2E);
                    unsigned short pb = f2bf(p);
                    lsum[r] += bf2f(pb);   // denominator matches rounded numerator
                    pt[w][quad * 4 + r][nt2 * 16 + l15] = pb;
                }
            }
            // O += P_half V_half  (k=32 exactly fills one MFMA)
            s16x8 pa = *(const s16x8*)&pt[w][l15][quad * 8];
            #pragma unroll
            for (int nt = 0; nt < 4; nt++) {
                s16x8 vf = *(const s16x8*)&vt[nt * 16 + l15][kh * 32 + quad * 8];
                accO[nt] = __builtin_amdgcn_mfma_f32_16x16x32_bf16(pa, vf, accO[nt], 0, 0, 0);
            }
        }
        __syncthreads();
    }

    // reduce row-sums across the 16 lanes sharing each row group
    #pragma unroll
    for (int r = 0; r < 4; r++) {
        float v = lsum[r];
        #pragma unroll
        for (int o = 1; o < 16; o <<= 1) v += __shfl_xor(v, o);
        lsum[r] = v;
    }
    // write partials: pOb[ck][b*4096+q][64] (bf16), pL[ck][b*4096+q] (fp32)
    #pragma unroll
    for (int r = 0; r < 4; r++) {
        int qrow = q0 + w * 16 + quad * 4 + r;
        size_t grow = (size_t)b * 4096 + qrow;
        #pragma unroll
        for (int nt = 0; nt < 4; nt++)
            pOb[((size_t)ck * 16384 + grow) * 64 + nt * 16 + l15] = f2bf(accO[nt][r]);
        if (l15 == 0)
            pL[(size_t)ck * 16384 + grow] = lsum[r];
    }
}

// ---------------------------------------------------------------------------
// Kernel 4: combine partials: out = (sum_c pOb) * mask / (sum_c pL)
// ---------------------------------------------------------------------------
__global__ __launch_bounds__(256) void combine_kernel(
    const unsigned short* __restrict__ pOb, const float* __restrict__ pL,
    const float* __restrict__ mask, float* __restrict__ out)
{
    int idx = blockIdx.x * 256 + threadIdx.x;   // 262144 = (b*4096+s)*16 + dgrp
    int q  = idx >> 4;
    int dg = idx & 15;
    fx4 s = (fx4){0.f, 0.f, 0.f, 0.f};
    float l = 0.f;
    #pragma unroll
    for (int c = 0; c < 8; c++) {
        u16x4 h = *(const u16x4*)(pOb + ((size_t)c * 16384 + q) * 64 + dg * 4);
        s.x += bf2f(h.x);
        s.y += bf2f(h.y);
        s.z += bf2f(h.z);
        s.w += bf2f(h.w);
        l += pL[(size_t)c * 16384 + q];
    }
    float scale = mask[q] / l;
    *(fx4*)(out + (size_t)q * 64 + dg * 4) = s * scale;
}

// ---------------------------------------------------------------------------
extern "C" void kernel_launch(void* const* d_in, const int* in_sizes, int n_in,
                              void* d_out, int out_size, void* d_ws, size_t ws_size,
                              hipStream_t stream)
{
    const float* X    = (const float*)d_in[0];
    const float* mask = (const float*)d_in[1];
    const float* Wq   = (const float*)d_in[2];
    const float* bq   = (const float*)d_in[3];
    const float* Wk   = (const float*)d_in[4];
    const float* bk   = (const float*)d_in[5];
    const float* Wv   = (const float*)d_in[6];
    const float* bv   = (const float*)d_in[7];
    float* out = (float*)d_out;

    char* ws = (char*)d_ws;
    unsigned short* q_hi  = (unsigned short*)(ws);                       // 2 MB
    unsigned short* q_lo  = (unsigned short*)(ws + (size_t)(2u << 20));  // 2 MB
    unsigned short* k_bf  = (unsigned short*)(ws + (size_t)(4u << 20));  // 2 MB
    unsigned short* vt_g  = (unsigned short*)(ws + (size_t)(6u << 20));  // 2 MB  [b][d][s]
    unsigned short* wt_hi = (unsigned short*)(ws + (size_t)(8u << 20));  // 384 KB
    unsigned short* wt_lo = (unsigned short*)(ws + (size_t)(8u << 20) + 393216);
    unsigned short* pOb   = (unsigned short*)(ws + (size_t)(9u << 20));  // 16 MB [8][16384][64] bf16
    float*          pL    = (float*)(ws + (size_t)(25u << 20));          // 512 KB [8][16384]

    hipLaunchKernelGGL(prep_w_kernel, dim3(768), dim3(256), 0, stream,
                       Wq, Wk, Wv, wt_hi, wt_lo);
    hipLaunchKernelGGL(proj_kernel, dim3(3, 256), dim3(512), 0, stream,
                       X, wt_hi, wt_lo, bq, bk, bv, q_hi, q_lo, k_bf, vt_g);
    hipLaunchKernelGGL(attn_kernel, dim3(64, 8, 4), dim3(256), 0, stream,
                       q_hi, q_lo, k_bf, vt_g, pOb, pL);
    hipLaunchKernelGGL(combine_kernel, dim3(1024), dim3(256), 0, stream,
                       pOb, pL, mask, out);
}

// Round 6
// 175.204 us; speedup vs baseline: 1.0934x; 1.0134x over previous
//
#include <hip/hip_runtime.h>

// B=4, S=4096, D_IN=1024, D_QK=D_V=64
// out = softmax(relu(XWq+bq) @ relu(XWk+bk)^T) @ relu(XWv+bv) * mask

typedef short s16x8 __attribute__((ext_vector_type(8)));   // 8 bf16 (4 VGPRs) MFMA frag
typedef float fx4   __attribute__((ext_vector_type(4)));   // MFMA accum frag
typedef unsigned short u16x4 __attribute__((ext_vector_type(4)));

#define LOG2E 1.4426950408889634f

__device__ __forceinline__ unsigned short f2bf(float x) {   // fp32 -> bf16 RTN
    unsigned int u = __float_as_uint(x);
    u += 0x7FFFu + ((u >> 16) & 1u);
    return (unsigned short)(u >> 16);
}
__device__ __forceinline__ float bf2f(unsigned short b) {
    return __uint_as_float(((unsigned int)b) << 16);
}

// ---------------------------------------------------------------------------
// Kernel 1: split W{q,k,v} [1024][64] fp32 into W^T hi/lo bf16 [3][64][1024].
// v2: LDS tile-transpose. Old version wrote 2 B at 2048 B stride (64
// transactions/wave-store, RMW sectors). Now: coalesced reads, LDS transpose,
// contiguous 32 B runs along k on the way out. grid (3 y, 16 k-tiles) x 256.
// ---------------------------------------------------------------------------
__global__ __launch_bounds__(256) void prep_w_kernel(
    const float* __restrict__ Wq, const float* __restrict__ Wk, const float* __restrict__ Wv,
    unsigned short* __restrict__ wt_hi, unsigned short* __restrict__ wt_lo)
{
    __shared__ __align__(16) unsigned short sh[64][72];   // [c][k_local]
    __shared__ __align__(16) unsigned short sl[64][72];

    const int y  = blockIdx.x;
    const int kt = blockIdx.y;
    const float* W = (y == 0) ? Wq : (y == 1) ? Wk : Wv;
    const int t  = threadIdx.x;

    // load: thread t reads 16 consecutive floats of row k = kt*64 + (t>>2)
    const int kl = t >> 2;
    const int c0 = (t & 3) * 16;
    const float* src = W + (size_t)(kt * 64 + kl) * 64 + c0;
    #pragma unroll
    for (int j = 0; j < 4; j++) {
        fx4 v = *(const fx4*)(src + j * 4);
        #pragma unroll
        for (int i = 0; i < 4; i++) {
            float x = v[i];
            unsigned short h = f2bf(x);
            unsigned short l = f2bf(x - bf2f(h));
            sh[c0 + j * 4 + i][kl] = h;
            sl[c0 + j * 4 + i][kl] = l;
        }
    }
    __syncthreads();

    // store: thread t writes c = t>>2, k-chunk (t&3)*16 (32 B contiguous)
    const int c  = t >> 2;
    const int k0 = (t & 3) * 16;
    size_t o = (size_t)(y * 64 + c) * 1024 + kt * 64 + k0;
    *(s16x8*)(wt_hi + o)     = *(const s16x8*)&sh[c][k0];
    *(s16x8*)(wt_hi + o + 8) = *(const s16x8*)&sh[c][k0 + 8];
    *(s16x8*)(wt_lo + o)     = *(const s16x8*)&sl[c][k0];
    *(s16x8*)(wt_lo + o + 8) = *(const s16x8*)&sl[c][k0 + 8];
}

// ---------------------------------------------------------------------------
// Kernel 2: projection. 1D grid 768, XCD-swizzled: the 3 y-blocks sharing an
// X m-tile get the same (id & 7) => same XCD under round-robin => X tile
// fetched once per XCD, not 3x. Block 512 (8 waves = 4 row-subtiles x 2
// col-halves), M-tile 64. Deep pipeline: X prefetch depth 4 (covers ~HBM
// latency), W depth 2 (L2-resident). Compensated bf16 MFMA (hh+hl+lh).
// y==0 -> q_hi/q_lo bf16; y==1 -> k bf16; y==2 -> V^T [b][d][s] bf16.
// ---------------------------------------------------------------------------
__global__ __launch_bounds__(512, 4) void proj_kernel(
    const float* __restrict__ X,
    const unsigned short* __restrict__ wt_hi, const unsigned short* __restrict__ wt_lo,
    const float* __restrict__ bq, const float* __restrict__ bk, const float* __restrict__ bv,
    unsigned short* __restrict__ q_hi, unsigned short* __restrict__ q_lo,
    unsigned short* __restrict__ k_bf, unsigned short* __restrict__ vt_g)
{
    __shared__ __align__(16) unsigned short a_buf[2][64][72];  // X tile hi/lo, +8 pad
    __shared__ __align__(16) unsigned short b_hi[64][72];      // W^T tile hi [col][k]
    __shared__ __align__(16) unsigned short b_lo[64][72];

    const int tid  = threadIdx.x;
    const int lane = tid & 63;
    const int w    = tid >> 6;      // 0..7
    const int quad = lane >> 4;
    const int l15  = lane & 15;
    const int rs   = w & 3;         // row-subtile (16 rows)
    const int ch   = w >> 2;        // col half (32 cols)

    // XCD swizzle decode: f = (m & 7) + 8*(y + 3*(m >> 3))
    const int f   = blockIdx.x;
    const int xcd = f & 7;
    const int jj  = f >> 3;
    const int y   = jj % 3;         // 0=q 1=k 2=v
    const int m0  = ((jj / 3) * 8 + xcd) * 64;

    fx4 acc[2];
    acc[0] = (fx4){0.f, 0.f, 0.f, 0.f};
    acc[1] = (fx4){0.f, 0.f, 0.f, 0.f};

    const int xrow = tid >> 4;        // 0..31
    const int xoff = (tid & 15) * 4;
    const int wrow = tid >> 3;        // 0..63
    const int woff = (tid & 7) * 8;

    const float* xb0 = X + (size_t)(m0 + xrow) * 1024 + xoff;
    const float* xb1 = X + (size_t)(m0 + xrow + 32) * 1024 + xoff;
    const size_t wb  = (size_t)(y * 64 + wrow) * 1024 + woff;

    // rolling prefetch buffers: X depth 4, W depth 2
    fx4   xr[4][2];
    s16x8 wrh[2], wrl[2];
    #pragma unroll
    for (int d = 0; d < 4; d++) {
        xr[d][0] = *(const fx4*)(xb0 + d * 64);
        xr[d][1] = *(const fx4*)(xb1 + d * 64);
    }
    #pragma unroll
    for (int d = 0; d < 2; d++) {
        wrh[d] = *(const s16x8*)(wt_hi + wb + d * 64);
        wrl[d] = *(const s16x8*)(wt_lo + wb + d * 64);
    }

    #pragma unroll 4
    for (int kc = 0; kc < 16; kc++) {
        if (kc) __syncthreads();   // prev iter's LDS readers done
        #pragma unroll
        for (int i = 0; i < 2; i++) {
            fx4 xv = xr[kc & 3][i];
            unsigned short h0 = f2bf(xv.x), h1 = f2bf(xv.y), h2 = f2bf(xv.z), h3 = f2bf(xv.w);
            unsigned short l0 = f2bf(xv.x - bf2f(h0)), l1 = f2bf(xv.y - bf2f(h1));
            unsigned short l2 = f2bf(xv.z - bf2f(h2)), l3 = f2bf(xv.w - bf2f(h3));
            *(u16x4*)&a_buf[0][xrow + i * 32][xoff] = (u16x4){h0, h1, h2, h3};
            *(u16x4*)&a_buf[1][xrow + i * 32][xoff] = (u16x4){l0, l1, l2, l3};
        }
        *(s16x8*)&b_hi[wrow][woff] = wrh[kc & 1];
        *(s16x8*)&b_lo[wrow][woff] = wrl[kc & 1];
        __syncthreads();

        // refill pipeline (latency hidden behind this + next 3 iters' MFMAs)
        if (kc < 12) {
            xr[kc & 3][0] = *(const fx4*)(xb0 + (kc + 4) * 64);
            xr[kc & 3][1] = *(const fx4*)(xb1 + (kc + 4) * 64);
        }
        if (kc < 14) {
            wrh[kc & 1] = *(const s16x8*)(wt_hi + wb + (kc + 2) * 64);
            wrl[kc & 1] = *(const s16x8*)(wt_lo + wb + (kc + 2) * 64);
        }

        s16x8 ah[2], al[2];
        #pragma unroll
        for (int ks = 0; ks < 2; ks++) {
            int r = rs * 16 + l15;
            ah[ks] = *(const s16x8*)&a_buf[0][r][ks * 32 + quad * 8];
            al[ks] = *(const s16x8*)&a_buf[1][r][ks * 32 + quad * 8];
        }
        #pragma unroll
        for (int nt = 0; nt < 2; nt++) {
            #pragma unroll
            for (int ks = 0; ks < 2; ks++) {
                s16x8 bh = *(const s16x8*)&b_hi[ch * 32 + nt * 16 + l15][ks * 32 + quad * 8];
                s16x8 bl = *(const s16x8*)&b_lo[ch * 32 + nt * 16 + l15][ks * 32 + quad * 8];
                acc[nt] = __builtin_amdgcn_mfma_f32_16x16x32_bf16(ah[ks], bh, acc[nt], 0, 0, 0);
                acc[nt] = __builtin_amdgcn_mfma_f32_16x16x32_bf16(ah[ks], bl, acc[nt], 0, 0, 0);
                acc[nt] = __builtin_amdgcn_mfma_f32_16x16x32_bf16(al[ks], bh, acc[nt], 0, 0, 0);
            }
        }
    }
    __syncthreads();   // all MFMA LDS reads done before vtr alias writes

    // epilogue: bias + relu, write per-matrix
    const float* bias = (y == 0) ? bq : (y == 1) ? bk : bv;
    const int b   = m0 >> 12;
    const int s0b = m0 & 4095;
    unsigned short* vtr = &a_buf[0][0][0];  // alias: [64 d][72]

    #pragma unroll
    for (int nt = 0; nt < 2; nt++) {
        int col = ch * 32 + nt * 16 + l15;
        float bb = bias[col];
        int rloc = rs * 16 + quad * 4;   // local row 0..63
        #pragma unroll
        for (int r = 0; r < 4; r++) {
            float v = acc[nt][r] + bb;
            v = fmaxf(v, 0.f);
            size_t grow = (size_t)(m0 + rloc + r);
            if (y == 0) {
                unsigned short h = f2bf(v);
                unsigned short l = f2bf(v - bf2f(h));
                q_hi[grow * 64 + col] = h;
                q_lo[grow * 64 + col] = l;
            } else if (y == 1) {
                k_bf[grow * 64 + col] = f2bf(v);
            } else {
                vtr[col * 72 + rloc + r] = f2bf(v);  // transpose via LDS
            }
        }
    }
    if (y == 2) {
        __syncthreads();
        int row = tid >> 3;          // d 0..63
        int off = (tid & 7) * 8;     // s chunk
        s16x8 vv = *(const s16x8*)&vtr[row * 72 + off];
        *(s16x8*)(vt_g + (size_t)(b * 64 + row) * 4096 + s0b + off) = vv;
    }
}

// ---------------------------------------------------------------------------
// Kernel 3: fused attention, KV-split. grid (64 qtiles, 8 chunks, 4 batch) =
// 2048 blocks. Block = 64 q-rows, 4 waves, 8 KV tiles each. LDS 23.5 KB
// (pt halved: keys processed in two 32-key halves) -> 6 blocks/CU.
// Writes UNNORMALIZED partial O (bf16) and row-sum l (fp32).
// No online max: q,k >= 0 post-relu => exp safe in fp32.
// ---------------------------------------------------------------------------
__global__ __launch_bounds__(256, 6) void attn_kernel(
    const unsigned short* __restrict__ q_hi, const unsigned short* __restrict__ q_lo,
    const unsigned short* __restrict__ k_bf, const unsigned short* __restrict__ vt_g,
    unsigned short* __restrict__ pOb, float* __restrict__ pL)
{
    __shared__ __align__(16) unsigned short kt[64][72];      // [key][dim]
    __shared__ __align__(16) unsigned short vt[64][72];      // [dim][key]  (V^T)
    __shared__ __align__(16) unsigned short pt[4][16][40];   // per-wave P [q][key half]

    const int tid  = threadIdx.x;
    const int lane = tid & 63;
    const int w    = tid >> 6;
    const int quad = lane >> 4;
    const int l15  = lane & 15;
    const int ck   = blockIdx.y;         // key chunk (512 keys)
    const int b    = blockIdx.z;
    const int q0   = blockIdx.x * 64;    // within batch

    // Q fragments (A layout: m=lane&15, k=quad*8+j), split hi/lo
    const size_t qoff = ((size_t)b * 4096 + q0 + w * 16 + l15) * 64 + quad * 8;
    s16x8 qh0 = *(const s16x8*)(q_hi + qoff);
    s16x8 qh1 = *(const s16x8*)(q_hi + qoff + 32);
    s16x8 ql0 = *(const s16x8*)(q_lo + qoff);
    s16x8 ql1 = *(const s16x8*)(q_lo + qoff + 32);

    fx4 accO[4];
    #pragma unroll
    for (int nt = 0; nt < 4; nt++) accO[nt] = (fx4){0.f, 0.f, 0.f, 0.f};
    float lsum[4] = {0.f, 0.f, 0.f, 0.f};

    const unsigned short* kgb = k_bf + (size_t)b * 4096 * 64;  // [s][64]
    const unsigned short* vgb = vt_g + (size_t)b * 64 * 4096;  // [d][s]

    const int srow = tid >> 3;        // 0..31
    const int soff = (tid & 7) * 8;

    for (int it = ck * 8; it < ck * 8 + 8; it++) {
        const unsigned short* kg = kgb + (size_t)it * 4096;    // 64 keys x 64 dims
        #pragma unroll
        for (int i = 0; i < 2; i++) {
            int row = srow + i * 32;
            *(s16x8*)&kt[row][soff] = *(const s16x8*)(kg + (size_t)row * 64 + soff);
            *(s16x8*)&vt[row][soff] = *(const s16x8*)(vgb + (size_t)row * 4096 + it * 64 + soff);
        }
        __syncthreads();

        #pragma unroll
        for (int kh = 0; kh < 2; kh++) {
            // S = Q K^T for 32-key half (hi/lo compensated)
            #pragma unroll
            for (int nt2 = 0; nt2 < 2; nt2++) {
                int key = kh * 32 + nt2 * 16 + l15;
                s16x8 k0 = *(const s16x8*)&kt[key][quad * 8];
                s16x8 k1 = *(const s16x8*)&kt[key][32 + quad * 8];
                fx4 sc = (fx4){0.f, 0.f, 0.f, 0.f};
                sc = __builtin_amdgcn_mfma_f32_16x16x32_bf16(qh0, k0, sc, 0, 0, 0);
                sc = __builtin_amdgcn_mfma_f32_16x16x32_bf16(ql0, k0, sc, 0, 0, 0);
                sc = __builtin_amdgcn_mfma_f32_16x16x32_bf16(qh1, k1, sc, 0, 0, 0);
                sc = __builtin_amdgcn_mfma_f32_16x16x32_bf16(ql1, k1, sc, 0, 0, 0);
                // P = exp(S) -> bf16 -> wave-private LDS (C -> A layout)
                #pragma unroll
                for (int r = 0; r < 4; r++) {
                    float p = __builtin_amdgcn_exp2f(sc[r] * LOG2E);
                    unsigned short pb = f2bf(p);
                    lsum[r] += bf2f(pb);   // denominator matches rounded numerator
                    pt[w][quad * 4 + r][nt2 * 16 + l15] = pb;
                }
            }
            // O += P_half V_half  (k=32 exactly fills one MFMA)
            s16x8 pa = *(const s16x8*)&pt[w][l15][quad * 8];
            #pragma unroll
            for (int nt = 0; nt < 4; nt++) {
                s16x8 vf = *(const s16x8*)&vt[nt * 16 + l15][kh * 32 + quad * 8];
                accO[nt] = __builtin_amdgcn_mfma_f32_16x16x32_bf16(pa, vf, accO[nt], 0, 0, 0);
            }
        }
        __syncthreads();
    }

    // reduce row-sums across the 16 lanes sharing each row group
    #pragma unroll
    for (int r = 0; r < 4; r++) {
        float v = lsum[r];
        #pragma unroll
        for (int o = 1; o < 16; o <<= 1) v += __shfl_xor(v, o);
        lsum[r] = v;
    }
    // write partials: pOb[ck][b*4096+q][64] (bf16), pL[ck][b*4096+q] (fp32)
    #pragma unroll
    for (int r = 0; r < 4; r++) {
        int qrow = q0 + w * 16 + quad * 4 + r;
        size_t grow = (size_t)b * 4096 + qrow;
        #pragma unroll
        for (int nt = 0; nt < 4; nt++)
            pOb[((size_t)ck * 16384 + grow) * 64 + nt * 16 + l15] = f2bf(accO[nt][r]);
        if (l15 == 0)
            pL[(size_t)ck * 16384 + grow] = lsum[r];
    }
}

// ---------------------------------------------------------------------------
// Kernel 4: combine partials: out = (sum_c pOb) * mask / (sum_c pL)
// ---------------------------------------------------------------------------
__global__ __launch_bounds__(256) void combine_kernel(
    const unsigned short* __restrict__ pOb, const float* __restrict__ pL,
    const float* __restrict__ mask, float* __restrict__ out)
{
    int idx = blockIdx.x * 256 + threadIdx.x;   // 262144 = (b*4096+s)*16 + dgrp
    int q  = idx >> 4;
    int dg = idx & 15;
    fx4 s = (fx4){0.f, 0.f, 0.f, 0.f};
    float l = 0.f;
    #pragma unroll
    for (int c = 0; c < 8; c++) {
        u16x4 h = *(const u16x4*)(pOb + ((size_t)c * 16384 + q) * 64 + dg * 4);
        s.x += bf2f(h.x);
        s.y += bf2f(h.y);
        s.z += bf2f(h.z);
        s.w += bf2f(h.w);
        l += pL[(size_t)c * 16384 + q];
    }
    float scale = mask[q] / l;
    *(fx4*)(out + (size_t)q * 64 + dg * 4) = s * scale;
}

// ---------------------------------------------------------------------------
extern "C" void kernel_launch(void* const* d_in, const int* in_sizes, int n_in,
                              void* d_out, int out_size, void* d_ws, size_t ws_size,
                              hipStream_t stream)
{
    const float* X    = (const float*)d_in[0];
    const float* mask = (const float*)d_in[1];
    const float* Wq   = (const float*)d_in[2];
    const float* bq   = (const float*)d_in[3];
    const float* Wk   = (const float*)d_in[4];
    const float* bk   = (const float*)d_in[5];
    const float* Wv   = (const float*)d_in[6];
    const float* bv   = (const float*)d_in[7];
    float* out = (float*)d_out;

    char* ws = (char*)d_ws;
    unsigned short* q_hi  = (unsigned short*)(ws);                       // 2 MB
    unsigned short* q_lo  = (unsigned short*)(ws + (size_t)(2u << 20));  // 2 MB
    unsigned short* k_bf  = (unsigned short*)(ws + (size_t)(4u << 20));  // 2 MB
    unsigned short* vt_g  = (unsigned short*)(ws + (size_t)(6u << 20));  // 2 MB  [b][d][s]
    unsigned short* wt_hi = (unsigned short*)(ws + (size_t)(8u << 20));  // 384 KB
    unsigned short* wt_lo = (unsigned short*)(ws + (size_t)(8u << 20) + 393216);
    unsigned short* pOb   = (unsigned short*)(ws + (size_t)(9u << 20));  // 16 MB [8][16384][64] bf16
    float*          pL    = (float*)(ws + (size_t)(25u << 20));          // 512 KB [8][16384]

    hipLaunchKernelGGL(prep_w_kernel, dim3(3, 16), dim3(256), 0, stream,
                       Wq, Wk, Wv, wt_hi, wt_lo);
    hipLaunchKernelGGL(proj_kernel, dim3(768), dim3(512), 0, stream,
                       X, wt_hi, wt_lo, bq, bk, bv, q_hi, q_lo, k_bf, vt_g);
    hipLaunchKernelGGL(attn_kernel, dim3(64, 8, 4), dim3(256), 0, stream,
                       q_hi, q_lo, k_bf, vt_g, pOb, pL);
    hipLaunchKernelGGL(combine_kernel, dim3(1024), dim3(256), 0, stream,
                       pOb, pL, mask, out);
}